// Round 3
// baseline (347.517 us; speedup 1.0000x reference)
//
#include <hip/hip_runtime.h>
#include <cmath>

#define Tseq 2048
#define Dm   1024
#define NHd  16
#define HDim 64
#define Mrows 4096   // B*T = 2*2048
#define QS   3072    // packed QKV row stride (f16 elems)
#define PAD  72      // LDS row stride (f16) for attention tiles
#define NSPLIT 16    // j-splits for the global row (i = T-1)

typedef _Float16 f16;
typedef _Float16 half8 __attribute__((ext_vector_type(8)));
typedef _Float16 half4 __attribute__((ext_vector_type(4)));
typedef float    floatx4 __attribute__((ext_vector_type(4)));

#define ASYNC_COPY16(g, l)                                                       \
  __builtin_amdgcn_global_load_lds((const __attribute__((address_space(1))) void*)(g), \
                                   (__attribute__((address_space(3))) void*)(l), 16, 0, 0)

// raw barrier with compiler memory fences (NO implicit vmcnt/lgkmcnt drain)
#define SBAR()                                    \
  do {                                            \
    asm volatile("" ::: "memory");                \
    __builtin_amdgcn_s_barrier();                 \
    asm volatile("" ::: "memory");                \
  } while (0)

// stage 256 rows x 64 cols (one operand tile) with 4 global_load_lds per thread
#define STAGE4(gptr, ldsbase)                                                    \
  do {                                                                           \
    _Pragma("unroll")                                                            \
    for (int i_ = 0; i_ < 4; ++i_)                                               \
      ASYNC_COPY16((gptr) + (size_t)(i_ * 64) * Kd, (ldsbase) + i_ * 4096 + ldsW); \
  } while (0)

// tanh-form GELU, one __expf. |err vs exact erf-GELU| <= ~3e-4.
__device__ __forceinline__ float gelu_f(float v) {
  const float u = 0.7978845608028654f * (v + 0.044715f * v * v * v);
  const float e = __expf(2.0f * u);
  return 0.5f * v * (2.0f - 2.0f / (e + 1.0f));
}

// ---------------------------------------------------------------- transpose + cast
__global__ __launch_bounds__(256) void transp_f16(const float* __restrict__ W,
                                                  f16* __restrict__ Wt, int K, int N) {
  __shared__ float tile[32][33];
  const int n0 = blockIdx.x * 32, k0 = blockIdx.y * 32;
  const int tx = threadIdx.x & 31, ty = threadIdx.x >> 5;
#pragma unroll
  for (int i = 0; i < 32; i += 8)
    tile[ty + i][tx] = W[(size_t)(k0 + ty + i) * N + n0 + tx];
  __syncthreads();
#pragma unroll
  for (int i = 0; i < 32; i += 8)
    Wt[(size_t)(n0 + ty + i) * K + k0 + tx] = (f16)tile[tx][ty + i];
}

// Q/K/V transposes in one launch (blockIdx.z selects the weight)
__global__ __launch_bounds__(256) void transp_qkv(const float* __restrict__ Wq,
                                                  const float* __restrict__ Wk,
                                                  const float* __restrict__ Wv,
                                                  f16* __restrict__ Wt) {
  __shared__ float tile[32][33];
  const float* W = (blockIdx.z == 0) ? Wq : (blockIdx.z == 1) ? Wk : Wv;
  f16* dst = Wt + (size_t)blockIdx.z * Dm * Dm;
  const int n0 = blockIdx.x * 32, k0 = blockIdx.y * 32;
  const int tx = threadIdx.x & 31, ty = threadIdx.x >> 5;
#pragma unroll
  for (int i = 0; i < 32; i += 8)
    tile[ty + i][tx] = W[(size_t)(k0 + ty + i) * Dm + n0 + tx];
  __syncthreads();
#pragma unroll
  for (int i = 0; i < 32; i += 8)
    dst[(size_t)(n0 + ty + i) * Dm + k0 + tx] = (f16)tile[tx][ty + i];
}

// ---------------------------------------------------------------- layernorm -> f16
__global__ __launch_bounds__(256) void ln_f16(const float* __restrict__ x,
                                              const float* __restrict__ g,
                                              const float* __restrict__ bb,
                                              f16* __restrict__ out) {
  const int row = blockIdx.x, t = threadIdx.x;
  const float4 v = ((const float4*)(x + (size_t)row * Dm))[t];
  float s  = v.x + v.y + v.z + v.w;
  float ss = v.x * v.x + v.y * v.y + v.z * v.z + v.w * v.w;
#pragma unroll
  for (int m = 32; m >= 1; m >>= 1) { s += __shfl_xor(s, m); ss += __shfl_xor(ss, m); }
  __shared__ float red[8];
  if ((t & 63) == 0) { red[t >> 6] = s; red[4 + (t >> 6)] = ss; }
  __syncthreads();
  const float S  = red[0] + red[1] + red[2] + red[3];
  const float SS = red[4] + red[5] + red[6] + red[7];
  const float mean = S * (1.0f / Dm);
  const float inv  = rsqrtf(SS * (1.0f / Dm) - mean * mean + 1e-5f);
  const float4 gg = ((const float4*)g)[t];
  const float4 bv = ((const float4*)bb)[t];
  half4 o;
  o.x = (f16)(((v.x - mean) * inv) * gg.x + bv.x);
  o.y = (f16)(((v.y - mean) * inv) * gg.y + bv.y);
  o.z = (f16)(((v.z - mean) * inv) * gg.z + bv.z);
  o.w = (f16)(((v.w - mean) * inv) * gg.w + bv.w);
  *((half4*)(out + (size_t)row * Dm) + t) = o;
}

// ---------------------------------------------------------------- split-K reduce (+ fused LN)
template <int NS>
__global__ __launch_bounds__(256) void reduce_ln(const f16* __restrict__ P,
                                                 const float* __restrict__ resid,
                                                 const float* __restrict__ bias,
                                                 const float* __restrict__ g,
                                                 const float* __restrict__ bb,
                                                 float* __restrict__ x1,
                                                 f16* __restrict__ h) {
  const int row = blockIdx.x, t = threadIdx.x;
  const size_t idx = (size_t)row * (Dm / 4) + t;
  const float4 r = ((const float4*)resid)[idx];
  const float4 b = ((const float4*)bias)[t];
  float4 o; o.x = r.x + b.x; o.y = r.y + b.y; o.z = r.z + b.z; o.w = r.w + b.w;
#pragma unroll
  for (int z = 0; z < NS; ++z) {
    const half4 p = ((const half4*)(P + (size_t)z * Mrows * Dm))[idx];
    o.x += (float)p[0]; o.y += (float)p[1]; o.z += (float)p[2]; o.w += (float)p[3];
  }
  ((float4*)x1)[idx] = o;
  float s  = o.x + o.y + o.z + o.w;
  float ss = o.x * o.x + o.y * o.y + o.z * o.z + o.w * o.w;
#pragma unroll
  for (int m = 32; m >= 1; m >>= 1) { s += __shfl_xor(s, m); ss += __shfl_xor(ss, m); }
  __shared__ float red[8];
  if ((t & 63) == 0) { red[t >> 6] = s; red[4 + (t >> 6)] = ss; }
  __syncthreads();
  const float S  = red[0] + red[1] + red[2] + red[3];
  const float SS = red[4] + red[5] + red[6] + red[7];
  const float mean = S * (1.0f / Dm);
  const float inv  = rsqrtf(SS * (1.0f / Dm) - mean * mean + 1e-5f);
  const float4 gg = ((const float4*)g)[t];
  const float4 bv = ((const float4*)bb)[t];
  half4 oh;
  oh[0] = (f16)(((o.x - mean) * inv) * gg.x + bv.x);
  oh[1] = (f16)(((o.y - mean) * inv) * gg.y + bv.y);
  oh[2] = (f16)(((o.z - mean) * inv) * gg.z + bv.z);
  oh[3] = (f16)(((o.w - mean) * inv) * gg.w + bv.w);
  ((half4*)h)[idx] = oh;
}

// plain split-K reduce: out = resid + bias + sum_z P[z]
template <int NS>
__global__ __launch_bounds__(256) void reduceK(const f16* __restrict__ P,
                                               const float* __restrict__ resid,
                                               const float* __restrict__ bias,
                                               float* __restrict__ out) {
  const int t = blockIdx.x * 256 + threadIdx.x;
  const int col4 = t & (Dm / 4 - 1);
  const float4 r = ((const float4*)resid)[t];
  const float4 b = ((const float4*)bias)[col4];
  float4 o; o.x = r.x + b.x; o.y = r.y + b.y; o.z = r.z + b.z; o.w = r.w + b.w;
#pragma unroll
  for (int z = 0; z < NS; ++z) {
    const half4 p = ((const half4*)(P + (size_t)z * Mrows * Dm))[t];
    o.x += (float)p[0]; o.y += (float)p[1]; o.z += (float)p[2]; o.w += (float)p[3];
  }
  ((float4*)out)[t] = o;
}

// ---------------------------------------------------------------- GEMM 128x128, BK=64 (f16 MFMA)
// Proven kernel; used for QKV (EPI 3) and Wo (EPI 5 split-K2).
template <int EPI, int LNZ>
__global__ __launch_bounds__(256, 4) void gemm_f16(const f16* __restrict__ A,
                                                   const f16* __restrict__ Bt,
                                                   int M, int N, int K, int kLen,
                                                   const float* __restrict__ bias,
                                                   f16* __restrict__ Ch) {
  constexpr int NZ = 1 << LNZ;
  __shared__ f16 As[128 * 64];   // 16 KB
  __shared__ f16 Bs[128 * 64];   // 16 KB
  const int tid = threadIdx.x;
  int bx, by, bz;
  if (EPI == 5) {
    const int lin = blockIdx.x;
    bz = lin & (NZ - 1);
    bx = (lin >> LNZ) & 7;        // N/128 == 8 for these GEMMs
    by = lin >> (LNZ + 3);
  } else {
    bx = blockIdx.x; by = blockIdx.y; bz = 0;
  }
  const int m0 = by * 128, n0 = bx * 128;
  const int kOff = bz * kLen;
  const int w = tid >> 6, l = tid & 63;
  const int wr = (w >> 1) * 64, wc = (w & 1) * 64;
  const int c = l & 15, qq = l >> 4;
  const int cx = c & 7;            // swizzle key for fragment reads
  const int srow = tid >> 3;       // 0..31 (staging row within 32-row group)
  const int scol = ((tid & 7) ^ (srow & 7)) * 8;  // swizzled global col (f16)

  floatx4 acc[4][4] = {};

  const f16* Ab = A + (size_t)(m0 + srow) * K + kOff + scol;
  const f16* Bb = Bt + (size_t)(n0 + srow) * K + kOff + scol;

  for (int k0 = 0; k0 < kLen; k0 += 64) {
    __syncthreads();
#pragma unroll
    for (int i = 0; i < 4; ++i) {
      ASYNC_COPY16(Ab + k0 + (size_t)(i * 32) * K, As + i * 2048 + w * 512);
      ASYNC_COPY16(Bb + k0 + (size_t)(i * 32) * K, Bs + i * 2048 + w * 512);
    }
    __syncthreads();
    half8 af[4][2], bfr[4][2];
#pragma unroll
    for (int t = 0; t < 4; ++t) {
      const int ra = (wr + t * 16 + c) * 64;
      af[t][0] = *(const half8*)&As[ra + ((qq ^ cx) * 8)];
      af[t][1] = *(const half8*)&As[ra + (((4 + qq) ^ cx) * 8)];
      const int rb = (wc + t * 16 + c) * 64;
      bfr[t][0] = *(const half8*)&Bs[rb + ((qq ^ cx) * 8)];
      bfr[t][1] = *(const half8*)&Bs[rb + (((4 + qq) ^ cx) * 8)];
    }
#pragma unroll
    for (int ti = 0; ti < 4; ++ti)
#pragma unroll
      for (int tj = 0; tj < 4; ++tj) {
        acc[ti][tj] = __builtin_amdgcn_mfma_f32_16x16x32_f16(af[ti][0], bfr[tj][0], acc[ti][tj], 0, 0, 0);
        acc[ti][tj] = __builtin_amdgcn_mfma_f32_16x16x32_f16(af[ti][1], bfr[tj][1], acc[ti][tj], 0, 0, 0);
      }
  }

  f16* Cw = (EPI == 5) ? (Ch + (size_t)bz * M * N) : Ch;
#pragma unroll
  for (int ti = 0; ti < 4; ++ti)
#pragma unroll
    for (int tj = 0; tj < 4; ++tj)
#pragma unroll
      for (int r = 0; r < 4; ++r) {
        const int row = m0 + wr + ti * 16 + qq * 4 + r;
        const int col = n0 + wc + tj * 16 + c;
        const size_t idx = (size_t)row * N + col;
        float v = acc[ti][tj][r];
        if (EPI == 2) {
          Cw[idx] = (f16)gelu_f(v + bias[col]);
        } else {
          Cw[idx] = (f16)v;
        }
      }
}

// ---------------------------------------------------------------- GEMM 256x256, BK=64, 8 waves
// v3: template-faithful same-phase schedule. Per K-tile: 4 phases of
//   { 4-or-8 ds_read_b128 issue -> (stage) -> s_barrier -> s_waitcnt lgkmcnt(0)
//     -> sched_barrier(0) -> setprio(1) -> 16 MFMA -> setprio(0) -> s_barrier }.
// Mechanism: the per-wave lgkmcnt(0) sits AFTER the barrier, so waves drain the
// shared LDS queue staggered; early waves' MFMA clusters cover late waves' drains
// (setprio arbitrates). Staging: ALL 8 global_load_lds of tile t+1 issued in ph1
// (3-phase latency window); one exact-counted vmcnt(0) per tile at end of ph4
// (outstanding = only t+1's loads, so no over-wait); first reads of t+1's LDS data
// are at t+1.ph1, after that vmcnt+barrier. Buffer safety: all reads of buf[cur^1]
// (tile t-1) completed before t-1.ph4's end barrier; staging into it starts t.ph1.
template <int EPI, int LNZ, int NT>
__global__ __launch_bounds__(512, 2) void gemm256(const f16* __restrict__ A,
                                                  const f16* __restrict__ Bt,
                                                  int M, int N, int Kd,
                                                  const float* __restrict__ bias,
                                                  f16* __restrict__ Ch) {
  __shared__ f16 As[2][256 * 64];  // 64 KB
  __shared__ f16 Bs[2][256 * 64];  // 64 KB

  // ---- block decode: bijective XCD swizzle (m204), z slowest for EPI5
  const int nwg = gridDim.x;
  const int lin = blockIdx.x;
  const int q8 = nwg >> 3, r8 = nwg & 7;
  const int xcd = lin & 7, idx8 = lin >> 3;
  const int wgid = (xcd < r8 ? xcd * (q8 + 1) : r8 * (q8 + 1) + (xcd - r8) * q8) + idx8;
  int bz = 0, rest = wgid;
  if (EPI == 5) {
    const int zLen = nwg >> LNZ;
    bz = wgid / zLen;
    rest = wgid - bz * zLen;
  }
  const int nbx = N >> 8;
  const int bx = rest % nbx, by = rest / nbx;
  const int m0 = by << 8, n0 = bx << 8;
  const int kOff = bz * (NT * 64);

  const int tid = threadIdx.x;
  const int w = tid >> 6, l = tid & 63;
  const int c = l & 15, qq = l >> 4, cx = c & 7;
  const int wr = (w >> 2) << 7;   // 0 / 128
  const int wc = (w & 3) << 6;    // 0 / 64 / 128 / 192
  const int srow = tid >> 3;      // 0..63
  const int scol = ((tid & 7) ^ (srow & 7)) << 3;  // pre-swizzled global col

  const f16* gA = A + (size_t)(m0 + srow) * Kd + kOff + scol;
  const f16* gB = Bt + (size_t)(n0 + srow) * Kd + kOff + scol;
  const int ldsW = (w << 3) * 64;  // wave's 8-row strip base (elems)

  floatx4 acc[8][4] = {};
  half8 aF[4], bF[4];

  // fragment loaders: mqb = row-quadrant base (0 or 4), ks4 = k-slice key (0 or 4)
  auto LDA = [&](half8* dst, const f16* base, int mqb, int ks4) {
#pragma unroll
    for (int i = 0; i < 4; ++i)
      dst[i] = *(const half8*)&base[(wr + (mqb + i) * 16 + c) * 64 + (((ks4 + qq) ^ cx) << 3)];
  };
  auto LDB = [&](half8* dst, const f16* base, int ks4) {
#pragma unroll
    for (int i = 0; i < 4; ++i)
      dst[i] = *(const half8*)&base[(wc + i * 16 + c) * 64 + (((ks4 + qq) ^ cx) << 3)];
  };
  auto MM = [&](int mqb, half8* af, half8* bf) {
#pragma unroll
    for (int i = 0; i < 4; ++i)
#pragma unroll
      for (int nq = 0; nq < 4; ++nq)
        acc[mqb + i][nq] =
            __builtin_amdgcn_mfma_f32_16x16x32_f16(af[i], bf[nq], acc[mqb + i][nq], 0, 0, 0);
  };

  // ---- prologue: stage tile 0, drain, barrier
  STAGE4(gA, &As[0][0]);
  STAGE4(gB, &Bs[0][0]);
  asm volatile("s_waitcnt vmcnt(0)" ::: "memory");
  SBAR();

  for (int t = 0; t < NT; ++t) {
    const int cur = t & 1;
    const f16* Ac = &As[cur][0];
    const f16* Bc = &Bs[cur][0];
    f16* An = &As[cur ^ 1][0];
    f16* Bn = &Bs[cur ^ 1][0];
    const bool more = (t + 1 < NT);

    // ==== ph1: read aA,b0; stage ALL of tile t+1; bar; lgkm0; MFMA acc[0-3] += aA*b0
    LDA(aF, Ac, 0, 0);
    LDB(bF, Bc, 0);
    if (more) {
      STAGE4(gA + (size_t)(t + 1) * 64, An);
      STAGE4(gB + (size_t)(t + 1) * 64, Bn);
    }
    SBAR();
    asm volatile("s_waitcnt lgkmcnt(0)" ::: "memory");
    __builtin_amdgcn_sched_barrier(0);
    __builtin_amdgcn_s_setprio(1);
    MM(0, aF, bF);
    __builtin_amdgcn_s_setprio(0);
    SBAR();

    // ==== ph2: read aB; bar; lgkm0; MFMA acc[4-7] += aB*b0
    LDA(aF, Ac, 4, 0);
    SBAR();
    asm volatile("s_waitcnt lgkmcnt(0)" ::: "memory");
    __builtin_amdgcn_sched_barrier(0);
    __builtin_amdgcn_s_setprio(1);
    MM(4, aF, bF);
    __builtin_amdgcn_s_setprio(0);
    SBAR();

    // ==== ph3: read aC,b1; bar; lgkm0; MFMA acc[0-3] += aC*b1
    LDA(aF, Ac, 0, 4);
    LDB(bF, Bc, 4);
    SBAR();
    asm volatile("s_waitcnt lgkmcnt(0)" ::: "memory");
    __builtin_amdgcn_sched_barrier(0);
    __builtin_amdgcn_s_setprio(1);
    MM(0, aF, bF);
    __builtin_amdgcn_s_setprio(0);
    SBAR();

    // ==== ph4: read aD; bar; lgkm0; MFMA acc[4-7] += aD*b1; vmcnt for t+1 residency
    LDA(aF, Ac, 4, 4);
    SBAR();
    asm volatile("s_waitcnt lgkmcnt(0)" ::: "memory");
    __builtin_amdgcn_sched_barrier(0);
    __builtin_amdgcn_s_setprio(1);
    MM(4, aF, bF);
    __builtin_amdgcn_s_setprio(0);
    if (more) asm volatile("s_waitcnt vmcnt(0)" ::: "memory");
    SBAR();
  }

  // ---- epilogue
  float bias_v[4] = {0.f, 0.f, 0.f, 0.f};
  if (EPI == 2) {
#pragma unroll
    for (int nq = 0; nq < 4; ++nq) bias_v[nq] = bias[n0 + wc + nq * 16 + c];
  }
  f16* Cw = (EPI == 5) ? (Ch + (size_t)bz * M * N) : Ch;
#pragma unroll
  for (int mq = 0; mq < 8; ++mq)
#pragma unroll
    for (int r = 0; r < 4; ++r) {
      const size_t rowb = (size_t)(m0 + wr + mq * 16 + qq * 4 + r) * N;
#pragma unroll
      for (int nq = 0; nq < 4; ++nq) {
        const int col = n0 + wc + nq * 16 + c;
        const float v = acc[mq][nq][r];
        if (EPI == 2) Cw[rowb + col] = (f16)gelu_f(v + bias_v[nq]);
        else          Cw[rowb + col] = (f16)v;
      }
    }
}

// ---------------------------------------------------------------- windowed attention (MFMA)
__global__ __launch_bounds__(256, 4) void attn_win(const f16* __restrict__ qkv,
                                                   f16* __restrict__ ao) {
  __shared__ f16 qs[64 * PAD];   // [i][d]
  __shared__ f16 ks[64 * PAD];   // [j][d]
  __shared__ f16 vts[64 * PAD];  // [d][j]  (transposed)
  __shared__ f16 ps[64 * PAD];   // [i][j]  wave-private row slices
  const int qt = blockIdx.x;
  const int b = blockIdx.y >> 4, hh = blockIdx.y & 15;
  const int q0 = qt * 64;
  const int tid = threadIdx.x, w = tid >> 6, l = tid & 63;
  const int c = l & 15, qq = l >> 4;
  const int wr = w * 16;
  const size_t base = ((size_t)b * Tseq) * QS + hh * HDim;
  const int rr = tid >> 2, ss = (tid & 3) * 16;

  {
    const f16* src = qkv + base + (size_t)(q0 + rr) * QS + ss;
    *(uint4*)&qs[rr * PAD + ss]     = *(const uint4*)src;
    *(uint4*)&qs[rr * PAD + ss + 8] = *(const uint4*)(src + 8);
  }

  float m_run[4], l_run[4];
  floatx4 oacc[4];
#pragma unroll
  for (int r = 0; r < 4; ++r) { m_run[r] = -INFINITY; l_run[r] = 0.f; }
#pragma unroll
  for (int td = 0; td < 4; ++td) oacc[td] = (floatx4){0.f, 0.f, 0.f, 0.f};

  int chunks[4]; int nch = 0;
  if (qt > 2) chunks[nch++] = 0;
  for (int ch = (qt - 2 > 0 ? qt - 2 : 0); ch <= qt; ++ch) chunks[nch++] = ch;

  for (int ci = 0; ci < nch; ++ci) {
    const int j0 = chunks[ci] * 64;
    __syncthreads();
    {
      const f16* srck = qkv + base + 1024 + (size_t)(j0 + rr) * QS + ss;
      *(uint4*)&ks[rr * PAD + ss]     = *(const uint4*)srck;
      *(uint4*)&ks[rr * PAD + ss + 8] = *(const uint4*)(srck + 8);
      const f16* srcv = qkv + base + 2048 + (size_t)(j0 + rr) * QS + ss;
      uint4 va0 = *(const uint4*)srcv;
      uint4 va1 = *(const uint4*)(srcv + 8);
      const f16* e0 = (const f16*)&va0;
      const f16* e1 = (const f16*)&va1;
#pragma unroll
      for (int i = 0; i < 8; ++i) vts[(ss + i) * PAD + rr] = e0[i];
#pragma unroll
      for (int i = 0; i < 8; ++i) vts[(ss + 8 + i) * PAD + rr] = e1[i];
    }
    __syncthreads();

    const half8 a0 = *(const half8*)&qs[(wr + c) * PAD + qq * 8];
    const half8 a1 = *(const half8*)&qs[(wr + c) * PAD + 32 + qq * 8];
    floatx4 sacc[4];
#pragma unroll
    for (int tj = 0; tj < 4; ++tj) {
      const half8 b0 = *(const half8*)&ks[(tj * 16 + c) * PAD + qq * 8];
      const half8 b1 = *(const half8*)&ks[(tj * 16 + c) * PAD + 32 + qq * 8];
      floatx4 s4 = {0.f, 0.f, 0.f, 0.f};
      s4 = __builtin_amdgcn_mfma_f32_16x16x32_f16(a0, b0, s4, 0, 0, 0);
      s4 = __builtin_amdgcn_mfma_f32_16x16x32_f16(a1, b1, s4, 0, 0, 0);
      sacc[tj] = s4;
    }

#pragma unroll
    for (int r = 0; r < 4; ++r) {
      const int ii = q0 + wr + qq * 4 + r;
      float sv[4];
      float mx = -INFINITY;
#pragma unroll
      for (int tj = 0; tj < 4; ++tj) {
        const int jj = j0 + tj * 16 + c;
        const bool allowed = (jj <= ii) && ((ii - jj) <= 128 || jj == 0);
        sv[tj] = allowed ? sacc[tj][r] * 0.125f : -INFINITY;
        mx = fmaxf(mx, sv[tj]);
      }
#pragma unroll
      for (int mm = 8; mm >= 1; mm >>= 1) mx = fmaxf(mx, __shfl_xor(mx, mm));
      const float mn = fmaxf(m_run[r], mx);
      const float alpha = (mn == -INFINITY) ? 1.f : __expf(m_run[r] - mn);
      float sum = 0.f;
      float p[4];
#pragma unroll
      for (int tj = 0; tj < 4; ++tj) { p[tj] = __expf(sv[tj] - mn); sum += p[tj]; }
#pragma unroll
      for (int mm = 8; mm >= 1; mm >>= 1) sum += __shfl_xor(sum, mm);
      l_run[r] = l_run[r] * alpha + sum;
      m_run[r] = mn;
#pragma unroll
      for (int td = 0; td < 4; ++td) oacc[td][r] *= alpha;
#pragma unroll
      for (int tj = 0; tj < 4; ++tj)
        ps[(wr + qq * 4 + r) * PAD + tj * 16 + c] = (f16)p[tj];
    }

    const half8 p0 = *(const half8*)&ps[(wr + c) * PAD + qq * 8];
    const half8 p1 = *(const half8*)&ps[(wr + c) * PAD + 32 + qq * 8];
#pragma unroll
    for (int td = 0; td < 4; ++td) {
      const half8 b0 = *(const half8*)&vts[(td * 16 + c) * PAD + qq * 8];
      const half8 b1 = *(const half8*)&vts[(td * 16 + c) * PAD + 32 + qq * 8];
      oacc[td] = __builtin_amdgcn_mfma_f32_16x16x32_f16(p0, b0, oacc[td], 0, 0, 0);
      oacc[td] = __builtin_amdgcn_mfma_f32_16x16x32_f16(p1, b1, oacc[td], 0, 0, 0);
    }
  }

#pragma unroll
  for (int td = 0; td < 4; ++td)
#pragma unroll
    for (int r = 0; r < 4; ++r) {
      const int ii = q0 + wr + qq * 4 + r;
      ao[((size_t)(b * Tseq + ii)) * Dm + hh * HDim + td * 16 + c] =
          (f16)(oacc[td][r] / l_run[r]);
    }
}

// ---------------------------------------------------------------- global row i = T-1 (split-j)
__global__ __launch_bounds__(256) void attn_row_part(const f16* __restrict__ qkv,
                                                     float* __restrict__ part) {
  const int bh = blockIdx.x, sp = blockIdx.y;
  const int b = bh >> 4, hh = bh & 15;
  const int tid = threadIdx.x;
  const size_t base = ((size_t)b * Tseq) * QS + hh * HDim;
  const int j0 = sp * (Tseq / NSPLIT);   // 128 keys per split
  __shared__ float qsh[64];
  __shared__ float ps[128];
  __shared__ float red[4];
  __shared__ float red2[4];
  __shared__ float oacc[4][64];
  if (tid < 64) qsh[tid] = (float)qkv[base + (size_t)(Tseq - 1) * QS + tid] * 0.125f;
  __syncthreads();
  float sv = -INFINITY;
  if (tid < 128) {
    const f16* kr = qkv + base + 1024 + (size_t)(j0 + tid) * QS;
    float a0 = 0.f;
#pragma unroll
    for (int d8 = 0; d8 < 8; ++d8) {
      const half8 kv = *(const half8*)(kr + d8 * 8);
#pragma unroll
      for (int e = 0; e < 8; ++e) a0 = fmaf((float)kv[e], qsh[d8 * 8 + e], a0);
    }
    sv = a0;  // row T-1: all j <= T-1 allowed
  }
  float mx = sv;
#pragma unroll
  for (int mm = 32; mm >= 1; mm >>= 1) mx = fmaxf(mx, __shfl_xor(mx, mm));
  if ((tid & 63) == 0) red[tid >> 6] = mx;
  __syncthreads();
  const float M = fmaxf(red[0], red[1]);  // waves 2,3 hold -inf
  float p = 0.f;
  if (tid < 128) { p = __expf(sv - M); ps[tid] = p; }
  float sum = p;
#pragma unroll
  for (int mm = 32; mm >= 1; mm >>= 1) sum += __shfl_xor(sum, mm);
  if ((tid & 63) == 0) red2[tid >> 6] = sum;
  __syncthreads();
  const float L = red2[0] + red2[1];
  const int d = tid & 63, pt = tid >> 6;
  const f16* vb = qkv + base + 2048 + d;
  float acc = 0.f;
  for (int j = pt * 32; j < pt * 32 + 32; ++j)
    acc = fmaf(ps[j], (float)vb[(size_t)(j0 + j) * QS], acc);
  oacc[pt][d] = acc;
  __syncthreads();
  if (tid < 64) {
    const float o = oacc[0][tid] + oacc[1][tid] + oacc[2][tid] + oacc[3][tid];
    float* dst = part + ((size_t)bh * NSPLIT + sp) * 66;
    dst[tid] = o;
    if (tid == 0) { dst[64] = M; dst[65] = L; }
  }
}

// Combine NSPLIT partials per (b,h) and write row T-1 of attnF.
__global__ __launch_bounds__(64) void attn_row_comb(const float* __restrict__ part,
                                                    f16* __restrict__ ao) {
  const int bh = blockIdx.x;
  const int b = bh >> 4, hh = bh & 15;
  const int tid = threadIdx.x;
  const float* pp = part + (size_t)bh * NSPLIT * 66;
  float M = -INFINITY;
#pragma unroll
  for (int s = 0; s < NSPLIT; ++s) M = fmaxf(M, pp[s * 66 + 64]);
  float L = 0.f, o = 0.f;
#pragma unroll
  for (int s = 0; s < NSPLIT; ++s) {
    const float wgt = __expf(pp[s * 66 + 64] - M);
    L += pp[s * 66 + 65] * wgt;
    o += pp[s * 66 + tid] * wgt;
  }
  ao[((size_t)(b * Tseq + Tseq - 1)) * Dm + hh * HDim + tid] = (f16)(o / L);
}

// ---------------------------------------------------------------- launch
extern "C" void kernel_launch(void* const* d_in, const int* in_sizes, int n_in,
                              void* d_out, int out_size, void* d_ws, size_t ws_size,
                              hipStream_t stream) {
  (void)in_sizes; (void)n_in; (void)out_size; (void)ws_size;
  const float* x    = (const float*)d_in[0];
  const float* ln1g = (const float*)d_in[1];
  const float* ln1b = (const float*)d_in[2];
  const float* ln2g = (const float*)d_in[3];
  const float* ln2b = (const float*)d_in[4];
  const float* Wq   = (const float*)d_in[5];
  const float* Wk   = (const float*)d_in[6];
  const float* Wv   = (const float*)d_in[7];
  const float* Wo   = (const float*)d_in[8];
  const float* bo   = (const float*)d_in[9];
  const float* W1   = (const float*)d_in[10];
  const float* b1   = (const float*)d_in[11];
  const float* W2   = (const float*)d_in[12];
  const float* b2   = (const float*)d_in[13];
  float* out = (float*)d_out;

  char* w0 = (char*)d_ws;
  size_t off = 0;
  auto take = [&](size_t bytes) -> char* {
    char* p = w0 + off;
    off += (bytes + 255) & ~(size_t)255;
    return p;
  };
  f16*   WqkvT = (f16*)take((size_t)3 * Dm * Dm * 2);  // Wq^T | Wk^T | Wv^T stacked
  f16*   WoT   = (f16*)take((size_t)Dm * Dm * 2);
  f16*   W1T   = (f16*)take((size_t)Dm * 4 * Dm * 2);
  f16*   W2T   = (f16*)take((size_t)Dm * 4 * Dm * 2);
  f16*   hF    = (f16*)take((size_t)Mrows * Dm * 2);
  f16*   qkvh  = (f16*)take((size_t)Mrows * QS * 2);   // 24 MiB
  f16*   attnF = (f16*)take((size_t)Mrows * Dm * 2);   // 8 MiB, contiguous after qkvh
  float* x1    = (float*)take((size_t)Mrows * Dm * 4);
  f16*   h2F   = (f16*)take((size_t)Mrows * Dm * 2);
  f16*   pbuf  = (f16*)take((size_t)4 * Mrows * Dm * 2);  // split-K f16 partials (32 MB)
  float* rowp  = (float*)take((size_t)32 * NSPLIT * 66 * 4);  // global-row partials
  f16*   ffn1F = qkvh;  // 4096x4096 f16 = 32 MiB == qkvh(24) + attnF(8) span

  const dim3 blk(256);
  const dim3 blk512(512);
  transp_qkv<<<dim3(Dm / 32, Dm / 32, 3), blk, 0, stream>>>(Wq, Wk, Wv, WqkvT);
  transp_f16<<<dim3(Dm / 32, Dm / 32), blk, 0, stream>>>(Wo, WoT, Dm, Dm);
  transp_f16<<<dim3(4 * Dm / 32, Dm / 32), blk, 0, stream>>>(W1, W1T, Dm, 4 * Dm);
  transp_f16<<<dim3(Dm / 32, 4 * Dm / 32), blk, 0, stream>>>(W2, W2T, 4 * Dm, Dm);

  ln_f16<<<Mrows, blk, 0, stream>>>(x, ln1g, ln1b, hF);

  // fused QKV: proven 128x128 kernel, 768 blocks (3/CU)
  gemm_f16<3, 0><<<dim3(QS / 128, Mrows / 128), blk, 0, stream>>>(
      hF, WqkvT, Mrows, QS, Dm, Dm, nullptr, qkvh);

  attn_row_part<<<dim3(2 * NHd, NSPLIT), blk, 0, stream>>>(qkvh, rowp);
  attn_win<<<dim3(Tseq / 64, 2 * NHd), blk, 0, stream>>>(qkvh, attnF);
  attn_row_comb<<<dim3(2 * NHd), dim3(64), 0, stream>>>(rowp, attnF);

  // Wo: split-K2 f16 partials, proven 128x128 kernel, 512 blocks
  gemm_f16<5, 1><<<dim3(512), blk, 0, stream>>>(
      attnF, WoT, Mrows, Dm, Dm, Dm / 2, nullptr, pbuf);
  reduce_ln<2><<<Mrows, blk, 0, stream>>>(pbuf, x, bo, ln2g, ln2b, x1, h2F);

  // FFN1: (4096x1024)@(1024x4096), 256 blocks of 256x256 (1/CU), GELU epilogue
  gemm256<2, 0, 16><<<dim3((Mrows / 256) * (4 * Dm / 256)), blk512, 0, stream>>>(
      h2F, W1T, Mrows, 4 * Dm, Dm, b1, ffn1F);

  // W2: split-K4 f16 partials (kLen=1024), 256 blocks of 256x256 (1/CU), then reduce
  gemm256<5, 2, 16><<<dim3(4 * (Mrows / 256) * (Dm / 256)), blk512, 0, stream>>>(
      ffn1F, W2T, Mrows, Dm, 4 * Dm, nullptr, pbuf);
  reduceK<4><<<Mrows * Dm / 1024, blk, 0, stream>>>(pbuf, x1, b2, out);
}

// Round 4
// 314.911 us; speedup vs baseline: 1.1035x; 1.1035x over previous
//
#include <hip/hip_runtime.h>
#include <cmath>

#define Tseq 2048
#define Dm   1024
#define NHd  16
#define HDim 64
#define Mrows 4096   // B*T = 2*2048
#define QS   3072    // packed QKV row stride (f16 elems)
#define PAD  72      // LDS row stride (f16) for attention tiles
#define NSPLIT 16    // j-splits for the global row (i = T-1)

typedef _Float16 f16;
typedef _Float16 half8 __attribute__((ext_vector_type(8)));
typedef _Float16 half4 __attribute__((ext_vector_type(4)));
typedef float    floatx4 __attribute__((ext_vector_type(4)));

#define ASYNC_COPY16(g, l)                                                       \
  __builtin_amdgcn_global_load_lds((const __attribute__((address_space(1))) void*)(g), \
                                   (__attribute__((address_space(3))) void*)(l), 16, 0, 0)

// tanh-form GELU, one __expf. |err vs exact erf-GELU| <= ~3e-4.
__device__ __forceinline__ float gelu_f(float v) {
  const float u = 0.7978845608028654f * (v + 0.044715f * v * v * v);
  const float e = __expf(2.0f * u);
  return 0.5f * v * (2.0f - 2.0f / (e + 1.0f));
}

// ---------------------------------------------------------------- fused prep
// One launch: 6 weight transposes (f32 -> f16^T) + LN1 (x -> hF).
// All sub-tasks are independent; fusing removes 4 launch gaps and fills the
// machine during the small transposes.
//   lin in [0,4096):      square transposes Wq/Wk/Wv/Wo (1024 blocks each)
//   lin in [4096,8192):   W1  (1024 x 4096) -> W1T
//   lin in [8192,12288):  W2  (4096 x 1024) -> W2T
//   lin in [12288,16384): LN1 row (4096 rows)
__device__ __forceinline__ void transp_body(const float* __restrict__ W,
                                            f16* __restrict__ Wt, int K, int N,
                                            int bx, int by, float (*tile)[33]) {
  const int n0 = bx * 32, k0 = by * 32;
  const int tx = threadIdx.x & 31, ty = threadIdx.x >> 5;
#pragma unroll
  for (int i = 0; i < 32; i += 8)
    tile[ty + i][tx] = W[(size_t)(k0 + ty + i) * N + n0 + tx];
  __syncthreads();
#pragma unroll
  for (int i = 0; i < 32; i += 8)
    Wt[(size_t)(n0 + ty + i) * K + k0 + tx] = (f16)tile[tx][ty + i];
}

__global__ __launch_bounds__(256) void prep(const float* __restrict__ Wq,
                                            const float* __restrict__ Wk,
                                            const float* __restrict__ Wv,
                                            const float* __restrict__ Wo,
                                            const float* __restrict__ W1,
                                            const float* __restrict__ W2,
                                            const float* __restrict__ x,
                                            const float* __restrict__ g,
                                            const float* __restrict__ bb,
                                            f16* __restrict__ WqkvT,
                                            f16* __restrict__ WoT,
                                            f16* __restrict__ W1T,
                                            f16* __restrict__ W2T,
                                            f16* __restrict__ hF) {
  __shared__ float tile[32][33];
  __shared__ float red[8];
  const int lin = blockIdx.x;
  if (lin < 4096) {
    const int wsel = lin >> 10, t = lin & 1023;
    const float* W = (wsel == 0) ? Wq : (wsel == 1) ? Wk : (wsel == 2) ? Wv : Wo;
    f16* dst = (wsel < 3) ? (WqkvT + (size_t)wsel * Dm * Dm) : WoT;
    transp_body(W, dst, Dm, Dm, t & 31, t >> 5, tile);
    return;
  }
  if (lin < 8192) {
    const int t = lin - 4096;
    transp_body(W1, W1T, Dm, 4 * Dm, t & 127, t >> 7, tile);
    return;
  }
  if (lin < 12288) {
    const int t = lin - 8192;
    transp_body(W2, W2T, 4 * Dm, Dm, t & 31, t >> 5, tile);
    return;
  }
  // ---- LN1 row
  const int row = lin - 12288, t = threadIdx.x;
  const float4 v = ((const float4*)(x + (size_t)row * Dm))[t];
  float s  = v.x + v.y + v.z + v.w;
  float ss = v.x * v.x + v.y * v.y + v.z * v.z + v.w * v.w;
#pragma unroll
  for (int m = 32; m >= 1; m >>= 1) { s += __shfl_xor(s, m); ss += __shfl_xor(ss, m); }
  if ((t & 63) == 0) { red[t >> 6] = s; red[4 + (t >> 6)] = ss; }
  __syncthreads();
  const float S  = red[0] + red[1] + red[2] + red[3];
  const float SS = red[4] + red[5] + red[6] + red[7];
  const float mean = S * (1.0f / Dm);
  const float inv  = rsqrtf(SS * (1.0f / Dm) - mean * mean + 1e-5f);
  const float4 gg = ((const float4*)g)[t];
  const float4 bv = ((const float4*)bb)[t];
  half4 o;
  o.x = (f16)(((v.x - mean) * inv) * gg.x + bv.x);
  o.y = (f16)(((v.y - mean) * inv) * gg.y + bv.y);
  o.z = (f16)(((v.z - mean) * inv) * gg.z + bv.z);
  o.w = (f16)(((v.w - mean) * inv) * gg.w + bv.w);
  *((half4*)(hF + (size_t)row * Dm) + t) = o;
}

// ---------------------------------------------------------------- split-K reduce (+ fused LN)
template <int NS>
__global__ __launch_bounds__(256) void reduce_ln(const f16* __restrict__ P,
                                                 const float* __restrict__ resid,
                                                 const float* __restrict__ bias,
                                                 const float* __restrict__ g,
                                                 const float* __restrict__ bb,
                                                 float* __restrict__ x1,
                                                 f16* __restrict__ h) {
  const int row = blockIdx.x, t = threadIdx.x;
  const size_t idx = (size_t)row * (Dm / 4) + t;
  const float4 r = ((const float4*)resid)[idx];
  const float4 b = ((const float4*)bias)[t];
  float4 o; o.x = r.x + b.x; o.y = r.y + b.y; o.z = r.z + b.z; o.w = r.w + b.w;
#pragma unroll
  for (int z = 0; z < NS; ++z) {
    const half4 p = ((const half4*)(P + (size_t)z * Mrows * Dm))[idx];
    o.x += (float)p[0]; o.y += (float)p[1]; o.z += (float)p[2]; o.w += (float)p[3];
  }
  ((float4*)x1)[idx] = o;
  float s  = o.x + o.y + o.z + o.w;
  float ss = o.x * o.x + o.y * o.y + o.z * o.z + o.w * o.w;
#pragma unroll
  for (int m = 32; m >= 1; m >>= 1) { s += __shfl_xor(s, m); ss += __shfl_xor(ss, m); }
  __shared__ float red[8];
  if ((t & 63) == 0) { red[t >> 6] = s; red[4 + (t >> 6)] = ss; }
  __syncthreads();
  const float S  = red[0] + red[1] + red[2] + red[3];
  const float SS = red[4] + red[5] + red[6] + red[7];
  const float mean = S * (1.0f / Dm);
  const float inv  = rsqrtf(SS * (1.0f / Dm) - mean * mean + 1e-5f);
  const float4 gg = ((const float4*)g)[t];
  const float4 bv = ((const float4*)bb)[t];
  half4 oh;
  oh[0] = (f16)(((o.x - mean) * inv) * gg.x + bv.x);
  oh[1] = (f16)(((o.y - mean) * inv) * gg.y + bv.y);
  oh[2] = (f16)(((o.z - mean) * inv) * gg.z + bv.z);
  oh[3] = (f16)(((o.w - mean) * inv) * gg.w + bv.w);
  ((half4*)h)[idx] = oh;
}

// plain split-K reduce: out = resid + bias + sum_z P[z]
template <int NS>
__global__ __launch_bounds__(256) void reduceK(const f16* __restrict__ P,
                                               const float* __restrict__ resid,
                                               const float* __restrict__ bias,
                                               float* __restrict__ out) {
  const int t = blockIdx.x * 256 + threadIdx.x;
  const int col4 = t & (Dm / 4 - 1);
  const float4 r = ((const float4*)resid)[t];
  const float4 b = ((const float4*)bias)[col4];
  float4 o; o.x = r.x + b.x; o.y = r.y + b.y; o.z = r.z + b.z; o.w = r.w + b.w;
#pragma unroll
  for (int z = 0; z < NS; ++z) {
    const half4 p = ((const half4*)(P + (size_t)z * Mrows * Dm))[t];
    o.x += (float)p[0]; o.y += (float)p[1]; o.z += (float)p[2]; o.w += (float)p[3];
  }
  ((float4*)out)[t] = o;
}

// ---------------------------------------------------------------- GEMM 128x128, BK=64 (f16 MFMA)
// EPI 2: gelu(C+bias)->f16.  EPI 3: C->f16.  EPI 5: f16 partial slab (split-K,
// flat grid, z in low bits -> each XCD gets one K-chunk's A-slab; verified R9).
// EPI 2/3: flat grid with chunked-XCD bx mapping: blocks lin==x (mod 8) land on
// XCD x (round-robin dispatch) and decode to bx in [x*chunk,(x+1)*chunk) -> each
// XCD's B working set is 128*chunk cols (<=1 MB) = L2-resident; A streams via L3.
template <int EPI, int LNZ>
__global__ __launch_bounds__(256, 4) void gemm_f16(const f16* __restrict__ A,
                                                   const f16* __restrict__ Bt,
                                                   int M, int N, int K, int kLen,
                                                   const float* __restrict__ bias,
                                                   f16* __restrict__ Ch) {
  constexpr int NZ = 1 << LNZ;
  __shared__ f16 As[128 * 64];   // 16 KB
  __shared__ f16 Bs[128 * 64];   // 16 KB
  const int tid = threadIdx.x;
  int bx, by, bz;
  if (EPI == 5) {
    const int lin = blockIdx.x;
    bz = lin & (NZ - 1);
    bx = (lin >> LNZ) & 7;        // N/128 == 8 for these GEMMs
    by = lin >> (LNZ + 3);
  } else {
    const int nbx = N >> 7, chunk = nbx >> 3;
    const int xcd = blockIdx.x & 7, idx = blockIdx.x >> 3;
    bx = xcd * chunk + idx % chunk;
    by = idx / chunk;
    bz = 0;
  }
  const int m0 = by * 128, n0 = bx * 128;
  const int kOff = bz * kLen;
  const int w = tid >> 6, l = tid & 63;
  const int wr = (w >> 1) * 64, wc = (w & 1) * 64;
  const int c = l & 15, qq = l >> 4;
  const int cx = c & 7;            // swizzle key for fragment reads
  const int srow = tid >> 3;       // 0..31 (staging row within 32-row group)
  const int scol = ((tid & 7) ^ (srow & 7)) * 8;  // swizzled global col (f16)

  floatx4 acc[4][4] = {};

  const f16* Ab = A + (size_t)(m0 + srow) * K + kOff + scol;
  const f16* Bb = Bt + (size_t)(n0 + srow) * K + kOff + scol;

  for (int k0 = 0; k0 < kLen; k0 += 64) {
    __syncthreads();
#pragma unroll
    for (int i = 0; i < 4; ++i) {
      ASYNC_COPY16(Ab + k0 + (size_t)(i * 32) * K, As + i * 2048 + w * 512);
      ASYNC_COPY16(Bb + k0 + (size_t)(i * 32) * K, Bs + i * 2048 + w * 512);
    }
    __syncthreads();
    half8 af[4][2], bfr[4][2];
#pragma unroll
    for (int t = 0; t < 4; ++t) {
      const int ra = (wr + t * 16 + c) * 64;
      af[t][0] = *(const half8*)&As[ra + ((qq ^ cx) * 8)];
      af[t][1] = *(const half8*)&As[ra + (((4 + qq) ^ cx) * 8)];
      const int rb = (wc + t * 16 + c) * 64;
      bfr[t][0] = *(const half8*)&Bs[rb + ((qq ^ cx) * 8)];
      bfr[t][1] = *(const half8*)&Bs[rb + (((4 + qq) ^ cx) * 8)];
    }
#pragma unroll
    for (int ti = 0; ti < 4; ++ti)
#pragma unroll
      for (int tj = 0; tj < 4; ++tj) {
        acc[ti][tj] = __builtin_amdgcn_mfma_f32_16x16x32_f16(af[ti][0], bfr[tj][0], acc[ti][tj], 0, 0, 0);
        acc[ti][tj] = __builtin_amdgcn_mfma_f32_16x16x32_f16(af[ti][1], bfr[tj][1], acc[ti][tj], 0, 0, 0);
      }
  }

  f16* Cw = (EPI == 5) ? (Ch + (size_t)bz * M * N) : Ch;
#pragma unroll
  for (int ti = 0; ti < 4; ++ti)
#pragma unroll
    for (int tj = 0; tj < 4; ++tj)
#pragma unroll
      for (int r = 0; r < 4; ++r) {
        const int row = m0 + wr + ti * 16 + qq * 4 + r;
        const int col = n0 + wc + tj * 16 + c;
        const size_t idx = (size_t)row * N + col;
        float v = acc[ti][tj][r];
        if (EPI == 2) {
          Cw[idx] = (f16)gelu_f(v + bias[col]);
        } else {
          Cw[idx] = (f16)v;
        }
      }
}

// ---------------------------------------------------------------- fused attention
// lin in [0,1024):     windowed attention (MFMA), qt = lin&31, (b,h) = lin>>5
// lin in [1024,1536):  global-row T-1 partials, bh = r&31, sp = r>>5
// Both only READ qkvh -> safe to co-schedule; fusing fills CUs better (win alone
// is 4 blocks/CU barrier-heavy; row_part rides along).
__global__ __launch_bounds__(256, 4) void attn_fused(const f16* __restrict__ qkv,
                                                     f16* __restrict__ ao,
                                                     float* __restrict__ part) {
  __shared__ f16 qs[64 * PAD];   // [i][d]
  __shared__ f16 ks[64 * PAD];   // [j][d]
  __shared__ f16 vts[64 * PAD];  // [d][j]  (transposed)
  __shared__ f16 ps[64 * PAD];   // [i][j]  wave-private row slices
  const int lin = blockIdx.x;
  const int tid = threadIdx.x;

  if (lin >= 1024) {
    // ---------------- global row i = T-1 (split-j), LDS overlaid on attn tiles
    const int r_ = lin - 1024;
    const int bh = r_ & 31, sp = r_ >> 5;
    const int b = bh >> 4, hh = bh & 15;
    const size_t base = ((size_t)b * Tseq) * QS + hh * HDim;
    const int j0 = sp * (Tseq / NSPLIT);   // 128 keys per split
    float* qsh  = (float*)qs;              // 64 floats
    float* psf  = (float*)ks;              // 128 floats
    float* red  = (float*)vts;             // 4
    float* red2 = red + 4;                 // 4
    float (*oaccp)[64] = (float(*)[64])ps; // 4 x 64 floats
    if (tid < 64) qsh[tid] = (float)qkv[base + (size_t)(Tseq - 1) * QS + tid] * 0.125f;
    __syncthreads();
    float sv = -INFINITY;
    if (tid < 128) {
      const f16* kr = qkv + base + 1024 + (size_t)(j0 + tid) * QS;
      float a0 = 0.f;
#pragma unroll
      for (int d8 = 0; d8 < 8; ++d8) {
        const half8 kv = *(const half8*)(kr + d8 * 8);
#pragma unroll
        for (int e = 0; e < 8; ++e) a0 = fmaf((float)kv[e], qsh[d8 * 8 + e], a0);
      }
      sv = a0;  // row T-1: all j <= T-1 allowed
    }
    float mx = sv;
#pragma unroll
    for (int mm = 32; mm >= 1; mm >>= 1) mx = fmaxf(mx, __shfl_xor(mx, mm));
    if ((tid & 63) == 0) red[tid >> 6] = mx;
    __syncthreads();
    const float M = fmaxf(red[0], red[1]);  // waves 2,3 hold -inf
    float p = 0.f;
    if (tid < 128) { p = __expf(sv - M); psf[tid] = p; }
    float sum = p;
#pragma unroll
    for (int mm = 32; mm >= 1; mm >>= 1) sum += __shfl_xor(sum, mm);
    if ((tid & 63) == 0) red2[tid >> 6] = sum;
    __syncthreads();
    const float L = red2[0] + red2[1];
    const int d = tid & 63, pt = tid >> 6;
    const f16* vb = qkv + base + 2048 + d;
    float acc = 0.f;
    for (int j = pt * 32; j < pt * 32 + 32; ++j)
      acc = fmaf(psf[j], (float)vb[(size_t)(j0 + j) * QS], acc);
    oaccp[pt][d] = acc;
    __syncthreads();
    if (tid < 64) {
      const float o = oaccp[0][tid] + oaccp[1][tid] + oaccp[2][tid] + oaccp[3][tid];
      float* dst = part + ((size_t)bh * NSPLIT + sp) * 66;
      dst[tid] = o;
      if (tid == 0) { dst[64] = M; dst[65] = L; }
    }
    return;
  }

  // ---------------- windowed attention (MFMA)
  const int qt = lin & 31;
  const int byv = lin >> 5;
  const int b = byv >> 4, hh = byv & 15;
  const int q0 = qt * 64;
  const int w = tid >> 6, l = tid & 63;
  const int c = l & 15, qq = l >> 4;
  const int wr = w * 16;
  const size_t base = ((size_t)b * Tseq) * QS + hh * HDim;
  const int rr = tid >> 2, ss = (tid & 3) * 16;

  {
    const f16* src = qkv + base + (size_t)(q0 + rr) * QS + ss;
    *(uint4*)&qs[rr * PAD + ss]     = *(const uint4*)src;
    *(uint4*)&qs[rr * PAD + ss + 8] = *(const uint4*)(src + 8);
  }

  float m_run[4], l_run[4];
  floatx4 oacc[4];
#pragma unroll
  for (int r = 0; r < 4; ++r) { m_run[r] = -INFINITY; l_run[r] = 0.f; }
#pragma unroll
  for (int td = 0; td < 4; ++td) oacc[td] = (floatx4){0.f, 0.f, 0.f, 0.f};

  int chunks[4]; int nch = 0;
  if (qt > 2) chunks[nch++] = 0;
  for (int ch = (qt - 2 > 0 ? qt - 2 : 0); ch <= qt; ++ch) chunks[nch++] = ch;

  for (int ci = 0; ci < nch; ++ci) {
    const int j0 = chunks[ci] * 64;
    __syncthreads();
    {
      const f16* srck = qkv + base + 1024 + (size_t)(j0 + rr) * QS + ss;
      *(uint4*)&ks[rr * PAD + ss]     = *(const uint4*)srck;
      *(uint4*)&ks[rr * PAD + ss + 8] = *(const uint4*)(srck + 8);
      const f16* srcv = qkv + base + 2048 + (size_t)(j0 + rr) * QS + ss;
      uint4 va0 = *(const uint4*)srcv;
      uint4 va1 = *(const uint4*)(srcv + 8);
      const f16* e0 = (const f16*)&va0;
      const f16* e1 = (const f16*)&va1;
#pragma unroll
      for (int i = 0; i < 8; ++i) vts[(ss + i) * PAD + rr] = e0[i];
#pragma unroll
      for (int i = 0; i < 8; ++i) vts[(ss + 8 + i) * PAD + rr] = e1[i];
    }
    __syncthreads();

    const half8 a0 = *(const half8*)&qs[(wr + c) * PAD + qq * 8];
    const half8 a1 = *(const half8*)&qs[(wr + c) * PAD + 32 + qq * 8];
    floatx4 sacc[4];
#pragma unroll
    for (int tj = 0; tj < 4; ++tj) {
      const half8 b0 = *(const half8*)&ks[(tj * 16 + c) * PAD + qq * 8];
      const half8 b1 = *(const half8*)&ks[(tj * 16 + c) * PAD + 32 + qq * 8];
      floatx4 s4 = {0.f, 0.f, 0.f, 0.f};
      s4 = __builtin_amdgcn_mfma_f32_16x16x32_f16(a0, b0, s4, 0, 0, 0);
      s4 = __builtin_amdgcn_mfma_f32_16x16x32_f16(a1, b1, s4, 0, 0, 0);
      sacc[tj] = s4;
    }

#pragma unroll
    for (int r = 0; r < 4; ++r) {
      const int ii = q0 + wr + qq * 4 + r;
      float sv[4];
      float mx = -INFINITY;
#pragma unroll
      for (int tj = 0; tj < 4; ++tj) {
        const int jj = j0 + tj * 16 + c;
        const bool allowed = (jj <= ii) && ((ii - jj) <= 128 || jj == 0);
        sv[tj] = allowed ? sacc[tj][r] * 0.125f : -INFINITY;
        mx = fmaxf(mx, sv[tj]);
      }
#pragma unroll
      for (int mm = 8; mm >= 1; mm >>= 1) mx = fmaxf(mx, __shfl_xor(mx, mm));
      const float mn = fmaxf(m_run[r], mx);
      const float alpha = (mn == -INFINITY) ? 1.f : __expf(m_run[r] - mn);
      float sum = 0.f;
      float p[4];
#pragma unroll
      for (int tj = 0; tj < 4; ++tj) { p[tj] = __expf(sv[tj] - mn); sum += p[tj]; }
#pragma unroll
      for (int mm = 8; mm >= 1; mm >>= 1) sum += __shfl_xor(sum, mm);
      l_run[r] = l_run[r] * alpha + sum;
      m_run[r] = mn;
#pragma unroll
      for (int td = 0; td < 4; ++td) oacc[td][r] *= alpha;
#pragma unroll
      for (int tj = 0; tj < 4; ++tj)
        ps[(wr + qq * 4 + r) * PAD + tj * 16 + c] = (f16)p[tj];
    }

    const half8 p0 = *(const half8*)&ps[(wr + c) * PAD + qq * 8];
    const half8 p1 = *(const half8*)&ps[(wr + c) * PAD + 32 + qq * 8];
#pragma unroll
    for (int td = 0; td < 4; ++td) {
      const half8 b0 = *(const half8*)&vts[(td * 16 + c) * PAD + qq * 8];
      const half8 b1 = *(const half8*)&vts[(td * 16 + c) * PAD + 32 + qq * 8];
      oacc[td] = __builtin_amdgcn_mfma_f32_16x16x32_f16(p0, b0, oacc[td], 0, 0, 0);
      oacc[td] = __builtin_amdgcn_mfma_f32_16x16x32_f16(p1, b1, oacc[td], 0, 0, 0);
    }
  }

#pragma unroll
  for (int td = 0; td < 4; ++td)
#pragma unroll
    for (int r = 0; r < 4; ++r) {
      const int ii = q0 + wr + qq * 4 + r;
      ao[((size_t)(b * Tseq + ii)) * Dm + hh * HDim + td * 16 + c] =
          (f16)(oacc[td][r] / l_run[r]);
    }
}

// Combine NSPLIT partials per (b,h) and write row T-1 of attnF.
__global__ __launch_bounds__(64) void attn_row_comb(const float* __restrict__ part,
                                                    f16* __restrict__ ao) {
  const int bh = blockIdx.x;
  const int b = bh >> 4, hh = bh & 15;
  const int tid = threadIdx.x;
  const float* pp = part + (size_t)bh * NSPLIT * 66;
  float M = -INFINITY;
#pragma unroll
  for (int s = 0; s < NSPLIT; ++s) M = fmaxf(M, pp[s * 66 + 64]);
  float L = 0.f, o = 0.f;
#pragma unroll
  for (int s = 0; s < NSPLIT; ++s) {
    const float wgt = __expf(pp[s * 66 + 64] - M);
    L += pp[s * 66 + 65] * wgt;
    o += pp[s * 66 + tid] * wgt;
  }
  ao[((size_t)(b * Tseq + Tseq - 1)) * Dm + hh * HDim + tid] = (f16)(o / L);
}

// ---------------------------------------------------------------- launch
extern "C" void kernel_launch(void* const* d_in, const int* in_sizes, int n_in,
                              void* d_out, int out_size, void* d_ws, size_t ws_size,
                              hipStream_t stream) {
  (void)in_sizes; (void)n_in; (void)out_size; (void)ws_size;
  const float* x    = (const float*)d_in[0];
  const float* ln1g = (const float*)d_in[1];
  const float* ln1b = (const float*)d_in[2];
  const float* ln2g = (const float*)d_in[3];
  const float* ln2b = (const float*)d_in[4];
  const float* Wq   = (const float*)d_in[5];
  const float* Wk   = (const float*)d_in[6];
  const float* Wv   = (const float*)d_in[7];
  const float* Wo   = (const float*)d_in[8];
  const float* bo   = (const float*)d_in[9];
  const float* W1   = (const float*)d_in[10];
  const float* b1   = (const float*)d_in[11];
  const float* W2   = (const float*)d_in[12];
  const float* b2   = (const float*)d_in[13];
  float* out = (float*)d_out;

  char* w0 = (char*)d_ws;
  size_t off = 0;
  auto take = [&](size_t bytes) -> char* {
    char* p = w0 + off;
    off += (bytes + 255) & ~(size_t)255;
    return p;
  };
  f16*   WqkvT = (f16*)take((size_t)3 * Dm * Dm * 2);  // Wq^T | Wk^T | Wv^T stacked
  f16*   WoT   = (f16*)take((size_t)Dm * Dm * 2);
  f16*   W1T   = (f16*)take((size_t)Dm * 4 * Dm * 2);
  f16*   W2T   = (f16*)take((size_t)Dm * 4 * Dm * 2);
  f16*   hF    = (f16*)take((size_t)Mrows * Dm * 2);
  f16*   qkvh  = (f16*)take((size_t)Mrows * QS * 2);   // 24 MiB
  f16*   attnF = (f16*)take((size_t)Mrows * Dm * 2);   // 8 MiB, contiguous after qkvh
  float* x1    = (float*)take((size_t)Mrows * Dm * 4);
  f16*   h2F   = (f16*)take((size_t)Mrows * Dm * 2);
  f16*   pbuf  = (f16*)take((size_t)4 * Mrows * Dm * 2);  // split-K f16 partials (32 MB)
  float* rowp  = (float*)take((size_t)32 * NSPLIT * 66 * 4);  // global-row partials
  f16*   ffn1F = qkvh;  // 4096x4096 f16 = 32 MiB == qkvh(24) + attnF(8) span

  const dim3 blk(256);

  // prep: 6 transposes + LN1 in one launch (16384 blocks)
  prep<<<dim3(16384), blk, 0, stream>>>(Wq, Wk, Wv, Wo, W1, W2, x, ln1g, ln1b,
                                        WqkvT, WoT, W1T, W2T, hF);

  // fused QKV: (4096x1024)@(1024x3072) -> qkvh; 768 blocks, chunked-XCD bx
  gemm_f16<3, 0><<<dim3(768), blk, 0, stream>>>(
      hF, WqkvT, Mrows, QS, Dm, Dm, nullptr, qkvh);

  // attention: windowed (1024 blocks) + global-row partials (512 blocks) fused
  attn_fused<<<dim3(1536), blk, 0, stream>>>(qkvh, attnF, rowp);
  attn_row_comb<<<dim3(2 * NHd), dim3(64), 0, stream>>>(rowp, attnF);

  // Wo: split-K2 f16 partials, flat grid with z in low bits (512 blocks)
  gemm_f16<5, 1><<<dim3(512), blk, 0, stream>>>(
      attnF, WoT, Mrows, Dm, Dm, Dm / 2, nullptr, pbuf);
  reduce_ln<2><<<Mrows, blk, 0, stream>>>(pbuf, x, bo, ln2g, ln2b, x1, h2F);

  // FFN1: N=4096, 1024 blocks, chunked-XCD bx, fast-GELU epilogue
  gemm_f16<2, 0><<<dim3(1024), blk, 0, stream>>>(
      h2F, W1T, Mrows, 4 * Dm, Dm, Dm, b1, ffn1F);

  // W2: split-K4 f16 partials, flat grid (1024 blocks), then out = x1 + b2 + sum(P)
  gemm_f16<5, 2><<<dim3(1024), blk, 0, stream>>>(
      ffn1F, W2T, Mrows, Dm, 4 * Dm, Dm, nullptr, pbuf);
  reduceK<4><<<Mrows * Dm / 1024, blk, 0, stream>>>(pbuf, x1, b2, out);
}